// Round 7
// baseline (356.891 us; speedup 1.0000x reference)
//
#include <hip/hip_runtime.h>
#include <math.h>

// ---------------------------------------------------------------------------
// GCN 2-layer, bucket-partitioned with LDS-accumulator aggregation (no CSR):
//   k1a:    512 edge-slice blocks histogram dst>>9 -> hist_t[bucket][block]
//   kscan1: per-bucket block: exclusive scan over 512 slice counts -> colpre_t
//   kscan2: exclusive scan over bucket totals -> bucket_base
//   k1b:    FAT: [scatter packed (src<<9|loc) into bucket-major staging]
//                || [h = x@W1 (unscaled) -> g1]
//   k2lite: per-bucket: LDS deg count -> dinv; scale own g1 rows by dinv
//   aggr1:  per-bucket: acc[512][17] LDS float atomics over edges, epilogue
//           relu/bias + W2 -> g2p (padded float4)
//   aggr2:  per-bucket: acc[512][5], epilogue bias + log_softmax -> out
// ---------------------------------------------------------------------------

#define BSH 9
#define BNODES 512
#define P1 512

// ---- k1a: per-slice bucket histogram ----
__global__ void k1a_count(const int* __restrict__ dst, int* __restrict__ hist_t,
                          int NBK, int E) {
    __shared__ int lh[256];
    int t = threadIdx.x;
    lh[t] = 0;
    __syncthreads();
    int slice = (E + P1 - 1) / P1;
    int e0 = blockIdx.x * slice, e1 = min(E, e0 + slice);
    for (int e = e0 + t; e < e1; e += 256)
        atomicAdd(&lh[dst[e] >> BSH], 1);
    __syncthreads();
    for (int i = t; i < NBK; i += 256)
        hist_t[(size_t)i * P1 + blockIdx.x] = lh[i];
}

// ---- kscan1: per bucket, exclusive scan over P1 slice counts ----
__global__ void kscan1(const int* __restrict__ hist_t, int* __restrict__ colpre_t,
                       int* __restrict__ btot, int NBK) {
    __shared__ int v[P1], part[256];
    int kb = blockIdx.x, t = threadIdx.x;
    v[t] = hist_t[(size_t)kb * P1 + t];
    v[t + 256] = hist_t[(size_t)kb * P1 + t + 256];
    __syncthreads();
    int a = v[2 * t], c = v[2 * t + 1];
    part[t] = a + c;
    __syncthreads();
    for (int o = 1; o < 256; o <<= 1) {
        int add = (t >= o) ? part[t - o] : 0;
        __syncthreads();
        part[t] += add;
        __syncthreads();
    }
    int pre = (t == 0) ? 0 : part[t - 1];
    colpre_t[(size_t)kb * P1 + 2 * t] = pre;
    colpre_t[(size_t)kb * P1 + 2 * t + 1] = pre + a;
    if (t == 255) btot[kb] = part[255];
}

// ---- kscan2: exclusive scan over bucket totals ----
__global__ void kscan2(const int* __restrict__ btot, int* __restrict__ bucket_base, int NBK) {
    __shared__ int s[256];
    int t = threadIdx.x;
    int orig = (t < NBK) ? btot[t] : 0;
    s[t] = orig;
    __syncthreads();
    for (int o = 1; o < 256; o <<= 1) {
        int add = (t >= o) ? s[t - o] : 0;
        __syncthreads();
        s[t] += add;
        __syncthreads();
    }
    if (t < NBK) {
        bucket_base[t] = s[t] - orig;
        if (t == NBK - 1) bucket_base[NBK] = s[t];
    }
}

// ---- k1b FAT: bucket-major scatter || gemm1 (unscaled) ----
__global__ void k1b_fat(const int* __restrict__ src, const int* __restrict__ dst,
                        const int* __restrict__ colpre_t, const int* __restrict__ bucket_base,
                        unsigned int* __restrict__ staging,
                        const float* __restrict__ x, const float* __restrict__ W1,
                        float4* __restrict__ g1v, int NBK, int n, int E) {
    __shared__ float4 sW4[512];  // 8 KB; scatter branch aliases as int[]
    int b = blockIdx.x;
    if (b < P1) {
        int* loff = (int*)sW4;           // [NBK]
        int* lcur = ((int*)sW4) + 1024;  // [NBK]
        for (int i = threadIdx.x; i < NBK; i += 256) {
            loff[i] = bucket_base[i] + colpre_t[(size_t)i * P1 + b];
            lcur[i] = 0;
        }
        __syncthreads();
        int slice = (E + P1 - 1) / P1;
        int e0 = b * slice, e1 = min(E, e0 + slice);
        for (int e = e0 + threadIdx.x; e < e1; e += 256) {
            int d = dst[e], s = src[e];
            int k = d >> BSH;
            int t = atomicAdd(&lcur[k], 1);
            staging[loff[k] + t] = ((unsigned int)s << BSH) | (unsigned int)(d & (BNODES - 1));
        }
    } else {
        int tid = threadIdx.x;
        for (int i = tid; i < 512; i += 256) sW4[i] = ((const float4*)W1)[i];
        __syncthreads();
        int idx = (b - P1) * 256 + tid;
        int row = idx >> 2, c4 = idx & 3;
        if (row >= n) return;
        const float4* xr = (const float4*)(x + (size_t)row * 128);
        float4 acc = make_float4(0.f, 0.f, 0.f, 0.f);
        for (int q = 0; q < 32; ++q) {
            float4 xv = xr[q];
            #pragma unroll
            for (int j = 0; j < 4; ++j) {
                float s = (j == 0) ? xv.x : (j == 1) ? xv.y : (j == 2) ? xv.z : xv.w;
                float4 w = sW4[(q * 4 + j) * 4 + c4];
                acc.x += s * w.x; acc.y += s * w.y; acc.z += s * w.z; acc.w += s * w.w;
            }
        }
        g1v[(size_t)row * 4 + c4] = acc;  // unscaled; k2lite applies dinv
    }
}

// ---- k2lite: per-bucket deg -> dinv, scale own g1 rows ----
__global__ void k2lite(const unsigned int* __restrict__ staging,
                       const int* __restrict__ bucket_base,
                       float* __restrict__ dinv, float4* __restrict__ g1v, int n) {
    __shared__ int lh[BNODES];
    __shared__ float ldv[BNODES];
    int kb = blockIdx.x, t = threadIdx.x;
    int node0 = kb << BSH;
    int nloc = min(BNODES, n - node0);
    int ebase = bucket_base[kb], ecnt = bucket_base[kb + 1] - ebase;
    lh[t] = 0; lh[t + 256] = 0;
    __syncthreads();
    for (int e = t; e < ecnt; e += 256)
        atomicAdd(&lh[staging[ebase + e] & (BNODES - 1)], 1);
    __syncthreads();
    for (int i = t; i < nloc; i += 256) {
        float dv = rsqrtf((float)(lh[i] + 1));  // +1 self-loop
        dinv[node0 + i] = dv;
        ldv[i] = dv;
    }
    __syncthreads();
    for (int j = t; j < nloc * 4; j += 256) {
        float dv = ldv[j >> 2];
        float4 v = g1v[(size_t)node0 * 4 + j];
        v.x *= dv; v.y *= dv; v.z *= dv; v.w *= dv;
        g1v[(size_t)node0 * 4 + j] = v;
    }
}

// ---- aggr1: per-bucket LDS accumulation + layer-1 epilogue + W2 -> g2p ----
#define ASTR 17  // padded row stride (floats) to spread banks
__global__ void __launch_bounds__(512) k_aggr1(
        const float4* __restrict__ g1v, const unsigned int* __restrict__ staging,
        const int* __restrict__ bucket_base, const float* __restrict__ dinv,
        const float* __restrict__ b1, const float* __restrict__ W2,
        float4* __restrict__ g2p, int n) {
    __shared__ float acc[BNODES * ASTR];  // 34816 B
    int kb = blockIdx.x, t = threadIdx.x;
    int node0 = kb << BSH;
    int nloc = min(BNODES, n - node0);
    int ebase = bucket_base[kb], ecnt = bucket_base[kb + 1] - ebase;
    for (int i = t; i < BNODES * ASTR; i += 512) acc[i] = 0.f;
    __syncthreads();
    // edge pass: 4 lanes per edge, lane c4 adds features [4c4, 4c4+4)
    int c4 = t & 3;
    for (int e = (t >> 2); e < ecnt; e += 128) {
        unsigned int p = staging[ebase + e];
        int loc = p & (BNODES - 1);
        int s = (int)(p >> BSH);
        float4 v = g1v[(size_t)s * 4 + c4];
        float* a = acc + loc * ASTR + c4 * 4;
        atomicAdd(a + 0, v.x);
        atomicAdd(a + 1, v.y);
        atomicAdd(a + 2, v.z);
        atomicAdd(a + 3, v.w);
    }
    __syncthreads();
    // epilogue: one thread per node
    for (int i = t; i < nloc; i += 512) {
        float di = dinv[node0 + i];
        const float* a = acc + i * ASTR;
        float o0 = 0.f, o1 = 0.f, o2 = 0.f;
        #pragma unroll
        for (int q = 0; q < 4; ++q) {
            float4 self = g1v[(size_t)(node0 + i) * 4 + q];
            float sv[4] = {self.x, self.y, self.z, self.w};
            #pragma unroll
            for (int j = 0; j < 4; ++j) {
                int c = q * 4 + j;
                float z = fmaxf(0.f, di * (a[c] + sv[j]) + b1[c]);
                o0 += z * W2[c * 3 + 0];
                o1 += z * W2[c * 3 + 1];
                o2 += z * W2[c * 3 + 2];
            }
        }
        g2p[node0 + i] = make_float4(di * o0, di * o1, di * o2, 0.f);
    }
}

// ---- aggr2: per-bucket LDS accumulation + bias + log_softmax -> out ----
#define ASTR2 5
__global__ void __launch_bounds__(512) k_aggr2(
        const float4* __restrict__ g2p, const unsigned int* __restrict__ staging,
        const int* __restrict__ bucket_base, const float* __restrict__ dinv,
        const float* __restrict__ b2, float* __restrict__ out, int n) {
    __shared__ float acc[BNODES * ASTR2];  // 10240 B
    int kb = blockIdx.x, t = threadIdx.x;
    int node0 = kb << BSH;
    int nloc = min(BNODES, n - node0);
    int ebase = bucket_base[kb], ecnt = bucket_base[kb + 1] - ebase;
    for (int i = t; i < BNODES * ASTR2; i += 512) acc[i] = 0.f;
    __syncthreads();
    for (int e = t; e < ecnt; e += 512) {
        unsigned int p = staging[ebase + e];
        int loc = p & (BNODES - 1);
        int s = (int)(p >> BSH);
        float4 g = g2p[s];
        float* a = acc + loc * ASTR2;
        atomicAdd(a + 0, g.x);
        atomicAdd(a + 1, g.y);
        atomicAdd(a + 2, g.z);
    }
    __syncthreads();
    for (int i = t; i < nloc; i += 512) {
        float di = dinv[node0 + i];
        float4 self = g2p[node0 + i];
        const float* a = acc + i * ASTR2;
        float a0 = di * (a[0] + self.x) + b2[0];
        float a1 = di * (a[1] + self.y) + b2[1];
        float a2 = di * (a[2] + self.z) + b2[2];
        float m = fmaxf(a0, fmaxf(a1, a2));
        float e0 = expf(a0 - m), e1 = expf(a1 - m), e2 = expf(a2 - m);
        float lse = logf(e0 + e1 + e2);
        out[(size_t)(node0 + i) * 3 + 0] = a0 - m - lse;
        out[(size_t)(node0 + i) * 3 + 1] = a1 - m - lse;
        out[(size_t)(node0 + i) * 3 + 2] = a2 - m - lse;
    }
}

// ======================== launch ========================
extern "C" void kernel_launch(void* const* d_in, const int* in_sizes, int n_in,
                              void* d_out, int out_size, void* d_ws, size_t ws_size,
                              hipStream_t stream) {
    const float* x  = (const float*)d_in[0];
    const int*   ei = (const int*)d_in[1];      // [2][E]
    const float* W1 = (const float*)d_in[2];    // [128][16]
    const float* b1 = (const float*)d_in[3];    // [16]
    const float* W2 = (const float*)d_in[4];    // [16][3]
    const float* b2 = (const float*)d_in[5];    // [3]
    float* out = (float*)d_out;

    const int n = in_sizes[0] / 128;   // 100000
    const int E = in_sizes[1] / 2;     // 1600000
    const int* src = ei;
    const int* dst = ei + E;

    const int NBK = (n + BNODES - 1) >> BSH;   // 196

    auto align = [](size_t v) { return (v + 255) & ~(size_t)255; };
    char* ws = (char*)d_ws;
    size_t o = 0;
    int* hist_t      = (int*)(ws + o); o = align(o + (size_t)NBK * P1 * 4);
    int* colpre_t    = (int*)(ws + o); o = align(o + (size_t)NBK * P1 * 4);
    int* btot        = (int*)(ws + o); o = align(o + (size_t)NBK * 4);
    int* bucket_base = (int*)(ws + o); o = align(o + (size_t)(NBK + 1) * 4);
    float* dinv      = (float*)(ws + o); o = align(o + (size_t)n * 4);
    unsigned int* staging = (unsigned int*)(ws + o); o = align(o + (size_t)E * 4);
    float* g1        = (float*)(ws + o); o = align(o + (size_t)16 * n * 4);
    float* g2p       = (float*)(ws + o); o = align(o + (size_t)4 * n * 4);

    const int B = 256;
    int gn4 = (4 * n + B - 1) / B;     // 1563 gemm blocks

    k1a_count<<<P1, B, 0, stream>>>(dst, hist_t, NBK, E);
    kscan1<<<NBK, B, 0, stream>>>(hist_t, colpre_t, btot, NBK);
    kscan2<<<1, B, 0, stream>>>(btot, bucket_base, NBK);
    k1b_fat<<<P1 + gn4, B, 0, stream>>>(src, dst, colpre_t, bucket_base, staging,
                                        x, W1, (float4*)g1, NBK, n, E);
    k2lite<<<NBK, B, 0, stream>>>(staging, bucket_base, dinv, (float4*)g1, n);
    k_aggr1<<<NBK, 512, 0, stream>>>((const float4*)g1, staging, bucket_base, dinv,
                                     b1, W2, (float4*)g2p, n);
    k_aggr2<<<NBK, 512, 0, stream>>>((const float4*)g2p, staging, bucket_base, dinv,
                                     b2, out, n);
}

// Round 8
// 182.807 us; speedup vs baseline: 1.9523x; 1.9523x over previous
//
#include <hip/hip_runtime.h>
#include <hip/hip_fp16.h>
#include <math.h>

// ---------------------------------------------------------------------------
// GCN 2-layer, bucket-partitioned CSR build + wide-parallel fp16 gathers.
//   k1a:    512 edge-slice blocks histogram dst>>9 -> hist_t[bucket][slice]
//   kscan1: per-bucket exclusive scan over slice counts -> colpre_t
//   kscan2: exclusive scan over bucket totals -> bucket_base
//   k1b:    FAT: [scatter packed (src<<9|loc) into bucket-major staging]
//                || [h = x@W1 (unscaled) -> g1h fp16]
//   k2:     per-bucket (512 thr): LDS hist+scan -> deg/dinv/row_start,
//           csr place via LDS tickets, scale g1h by dinv in place
//   gather1: 16 lanes/node (4 edge-split x 4 feat-split), fp16 msgs,
//            relu/bias + W2 -> g2h (fp16x4)
//   gather2: 16 lanes/node edge-split, bias + log_softmax -> out (fp32)
// ---------------------------------------------------------------------------

#define BSH 9
#define BNODES 512
#define P1 512

struct alignas(8) Half4 { __half x, y, z, w; };

// ---- k1a: per-slice bucket histogram ----
__global__ void k1a_count(const int* __restrict__ dst, int* __restrict__ hist_t,
                          int NBK, int E) {
    __shared__ int lh[256];
    int t = threadIdx.x;
    lh[t] = 0;
    __syncthreads();
    int slice = (E + P1 - 1) / P1;
    int e0 = blockIdx.x * slice, e1 = min(E, e0 + slice);
    for (int e = e0 + t; e < e1; e += 256)
        atomicAdd(&lh[dst[e] >> BSH], 1);
    __syncthreads();
    for (int i = t; i < NBK; i += 256)
        hist_t[(size_t)i * P1 + blockIdx.x] = lh[i];
}

// ---- kscan1: per bucket, exclusive scan over P1 slice counts ----
__global__ void kscan1(const int* __restrict__ hist_t, int* __restrict__ colpre_t,
                       int* __restrict__ btot, int NBK) {
    __shared__ int v[P1], part[256];
    int kb = blockIdx.x, t = threadIdx.x;
    v[t] = hist_t[(size_t)kb * P1 + t];
    v[t + 256] = hist_t[(size_t)kb * P1 + t + 256];
    __syncthreads();
    int a = v[2 * t], c = v[2 * t + 1];
    part[t] = a + c;
    __syncthreads();
    for (int o = 1; o < 256; o <<= 1) {
        int add = (t >= o) ? part[t - o] : 0;
        __syncthreads();
        part[t] += add;
        __syncthreads();
    }
    int pre = (t == 0) ? 0 : part[t - 1];
    colpre_t[(size_t)kb * P1 + 2 * t] = pre;
    colpre_t[(size_t)kb * P1 + 2 * t + 1] = pre + a;
    if (t == 255) btot[kb] = part[255];
}

// ---- kscan2: exclusive scan over bucket totals ----
__global__ void kscan2(const int* __restrict__ btot, int* __restrict__ bucket_base, int NBK) {
    __shared__ int s[256];
    int t = threadIdx.x;
    int orig = (t < NBK) ? btot[t] : 0;
    s[t] = orig;
    __syncthreads();
    for (int o = 1; o < 256; o <<= 1) {
        int add = (t >= o) ? s[t - o] : 0;
        __syncthreads();
        s[t] += add;
        __syncthreads();
    }
    if (t < NBK) {
        bucket_base[t] = s[t] - orig;
        if (t == NBK - 1) bucket_base[NBK] = s[t];
    }
}

// ---- k1b FAT: bucket-major scatter || gemm1 -> g1h (unscaled fp16) ----
__global__ void k1b_fat(const int* __restrict__ src, const int* __restrict__ dst,
                        const int* __restrict__ colpre_t, const int* __restrict__ bucket_base,
                        unsigned int* __restrict__ staging,
                        const float* __restrict__ x, const float* __restrict__ W1,
                        Half4* __restrict__ g1h, int NBK, int n, int E) {
    __shared__ float4 sW4[512];  // 8 KB; scatter branch aliases as int[]
    int b = blockIdx.x;
    if (b < P1) {
        int* loff = (int*)sW4;           // [NBK]
        int* lcur = ((int*)sW4) + 1024;  // [NBK]
        for (int i = threadIdx.x; i < NBK; i += 256) {
            loff[i] = bucket_base[i] + colpre_t[(size_t)i * P1 + b];
            lcur[i] = 0;
        }
        __syncthreads();
        int slice = (E + P1 - 1) / P1;
        int e0 = b * slice, e1 = min(E, e0 + slice);
        for (int e = e0 + threadIdx.x; e < e1; e += 256) {
            int d = dst[e], s = src[e];
            int k = d >> BSH;
            int t = atomicAdd(&lcur[k], 1);
            staging[loff[k] + t] = ((unsigned int)s << BSH) | (unsigned int)(d & (BNODES - 1));
        }
    } else {
        int tid = threadIdx.x;
        for (int i = tid; i < 512; i += 256) sW4[i] = ((const float4*)W1)[i];
        __syncthreads();
        int idx = (b - P1) * 256 + tid;
        int row = idx >> 2, c4 = idx & 3;
        if (row >= n) return;
        const float4* xr = (const float4*)(x + (size_t)row * 128);
        float4 acc = make_float4(0.f, 0.f, 0.f, 0.f);
        for (int q = 0; q < 32; ++q) {
            float4 xv = xr[q];
            #pragma unroll
            for (int j = 0; j < 4; ++j) {
                float s = (j == 0) ? xv.x : (j == 1) ? xv.y : (j == 2) ? xv.z : xv.w;
                float4 w = sW4[(q * 4 + j) * 4 + c4];
                acc.x += s * w.x; acc.y += s * w.y; acc.z += s * w.z; acc.w += s * w.w;
            }
        }
        Half4 h;
        h.x = __float2half(acc.x); h.y = __float2half(acc.y);
        h.z = __float2half(acc.z); h.w = __float2half(acc.w);
        g1h[(size_t)row * 4 + c4] = h;   // unscaled; k2 applies dinv
    }
}

// ---- k2: per-bucket CSR + node meta + g1h scaling (512 threads) ----
__global__ void __launch_bounds__(512) k2_bucket(
        const unsigned int* __restrict__ staging, const int* __restrict__ bucket_base,
        int* __restrict__ csr, int* __restrict__ deg, float* __restrict__ dinv,
        int* __restrict__ row_start, Half4* __restrict__ g1h, int n) {
    __shared__ int lh[BNODES], sc[BNODES], lcur[BNODES];
    __shared__ float ldv[BNODES];
    int kb = blockIdx.x, t = threadIdx.x;
    int node0 = kb << BSH;
    int nloc = min(BNODES, n - node0);
    int ebase = bucket_base[kb], ecnt = bucket_base[kb + 1] - ebase;
    lh[t] = 0; lcur[t] = 0;
    __syncthreads();
    for (int e = t; e < ecnt; e += 512)
        atomicAdd(&lh[staging[ebase + e] & (BNODES - 1)], 1);
    __syncthreads();
    int own = lh[t];
    sc[t] = own;
    __syncthreads();
    for (int o = 1; o < 512; o <<= 1) {   // inclusive scan
        int add = (t >= o) ? sc[t - o] : 0;
        __syncthreads();
        sc[t] += add;
        __syncthreads();
    }
    int excl = sc[t] - own;
    if (t < nloc) {
        deg[node0 + t] = own;
        row_start[node0 + t] = ebase + excl;
        float dv = rsqrtf((float)(own + 1));  // +1 self-loop
        dinv[node0 + t] = dv;
        ldv[t] = dv;
    }
    sc[t] = excl;   // reuse as row base for placement
    __syncthreads();
    for (int e = t; e < ecnt; e += 512) {
        unsigned int p = staging[ebase + e];
        int loc = p & (BNODES - 1);
        int s = (int)(p >> BSH);
        int tk = atomicAdd(&lcur[loc], 1);
        csr[ebase + sc[loc] + tk] = s;
    }
    // scale this bucket's g1h rows by dinv (in place)
    for (int j = t; j < nloc * 4; j += 512) {
        float dv = ldv[j >> 2];
        Half4 v = g1h[(size_t)node0 * 4 + j];
        v.x = __float2half(__half2float(v.x) * dv);
        v.y = __float2half(__half2float(v.y) * dv);
        v.z = __float2half(__half2float(v.z) * dv);
        v.w = __float2half(__half2float(v.w) * dv);
        g1h[(size_t)node0 * 4 + j] = v;
    }
}

// ---- gather1: 16 lanes/node (esplit 4 x c4 4), fp16 msgs, epilogue -> g2h ----
__global__ void k_gather1(const Half4* __restrict__ g1h, const int* __restrict__ csr,
                          const int* __restrict__ row_start, const int* __restrict__ deg,
                          const float* __restrict__ dinv, const float* __restrict__ b1,
                          const float* __restrict__ W2, Half4* __restrict__ g2h, int n) {
    int idx = blockIdx.x * 256 + threadIdx.x;
    int i = idx >> 4, t15 = idx & 15;
    if (i >= n) return;
    int esplit = t15 >> 2, c4 = t15 & 3;
    int off = row_start[i], dg = deg[i];
    float ax = 0.f, ay = 0.f, az = 0.f, aw = 0.f;
    if (esplit == 0) {  // self term once
        Half4 sh = g1h[(size_t)i * 4 + c4];
        ax = __half2float(sh.x); ay = __half2float(sh.y);
        az = __half2float(sh.z); aw = __half2float(sh.w);
    }
    for (int k = esplit; k < dg; k += 4) {
        int s = csr[off + k];
        Half4 v = g1h[(size_t)s * 4 + c4];
        ax += __half2float(v.x); ay += __half2float(v.y);
        az += __half2float(v.z); aw += __half2float(v.w);
    }
    // reduce over esplit (lanes differ in bits 2,3)
    ax += __shfl_xor(ax, 4); ax += __shfl_xor(ax, 8);
    ay += __shfl_xor(ay, 4); ay += __shfl_xor(ay, 8);
    az += __shfl_xor(az, 4); az += __shfl_xor(az, 8);
    aw += __shfl_xor(aw, 4); aw += __shfl_xor(aw, 8);
    float di = dinv[i];
    float z0 = fmaxf(0.f, di * ax + b1[c4 * 4 + 0]);
    float z1 = fmaxf(0.f, di * ay + b1[c4 * 4 + 1]);
    float z2 = fmaxf(0.f, di * az + b1[c4 * 4 + 2]);
    float z3 = fmaxf(0.f, di * aw + b1[c4 * 4 + 3]);
    const float* w = W2 + c4 * 12;
    float o0 = z0 * w[0] + z1 * w[3] + z2 * w[6] + z3 * w[9];
    float o1 = z0 * w[1] + z1 * w[4] + z2 * w[7] + z3 * w[10];
    float o2 = z0 * w[2] + z1 * w[5] + z2 * w[8] + z3 * w[11];
    // reduce over c4 (bits 0,1)
    o0 += __shfl_xor(o0, 1); o0 += __shfl_xor(o0, 2);
    o1 += __shfl_xor(o1, 1); o1 += __shfl_xor(o1, 2);
    o2 += __shfl_xor(o2, 1); o2 += __shfl_xor(o2, 2);
    if (t15 == 0) {
        Half4 g;
        g.x = __float2half(di * o0); g.y = __float2half(di * o1);
        g.z = __float2half(di * o2); g.w = __float2half(0.f);
        g2h[i] = g;
    }
}

// ---- gather2: 16 lanes/node edge-split, bias + log_softmax -> out ----
__global__ void k_gather2(const Half4* __restrict__ g2h, const int* __restrict__ csr,
                          const int* __restrict__ row_start, const int* __restrict__ deg,
                          const float* __restrict__ dinv, const float* __restrict__ b2,
                          float* __restrict__ out, int n) {
    int idx = blockIdx.x * 256 + threadIdx.x;
    int i = idx >> 4, l = idx & 15;
    if (i >= n) return;
    int off = row_start[i], dg = deg[i];
    float v0 = 0.f, v1 = 0.f, v2 = 0.f;
    if (l == 0) {  // self term
        Half4 s = g2h[i];
        v0 = __half2float(s.x); v1 = __half2float(s.y); v2 = __half2float(s.z);
    }
    for (int e = l; e < dg; e += 16) {
        int s = csr[off + e];
        Half4 g = g2h[s];
        v0 += __half2float(g.x); v1 += __half2float(g.y); v2 += __half2float(g.z);
    }
    #pragma unroll
    for (int o = 1; o < 16; o <<= 1) {
        v0 += __shfl_xor(v0, o);
        v1 += __shfl_xor(v1, o);
        v2 += __shfl_xor(v2, o);
    }
    if (l >= 3) return;
    float di = dinv[i];
    float a0 = di * v0 + b2[0];
    float a1 = di * v1 + b2[1];
    float a2 = di * v2 + b2[2];
    float m = fmaxf(a0, fmaxf(a1, a2));
    float lse = logf(expf(a0 - m) + expf(a1 - m) + expf(a2 - m));
    float r = (l == 0) ? a0 : (l == 1) ? a1 : a2;
    out[(size_t)i * 3 + l] = r - m - lse;
}

// ======================== launch ========================
extern "C" void kernel_launch(void* const* d_in, const int* in_sizes, int n_in,
                              void* d_out, int out_size, void* d_ws, size_t ws_size,
                              hipStream_t stream) {
    const float* x  = (const float*)d_in[0];
    const int*   ei = (const int*)d_in[1];      // [2][E]
    const float* W1 = (const float*)d_in[2];    // [128][16]
    const float* b1 = (const float*)d_in[3];    // [16]
    const float* W2 = (const float*)d_in[4];    // [16][3]
    const float* b2 = (const float*)d_in[5];    // [3]
    float* out = (float*)d_out;

    const int n = in_sizes[0] / 128;   // 100000
    const int E = in_sizes[1] / 2;     // 1600000
    const int* src = ei;
    const int* dst = ei + E;

    const int NBK = (n + BNODES - 1) >> BSH;   // 196

    auto align = [](size_t v) { return (v + 255) & ~(size_t)255; };
    char* ws = (char*)d_ws;
    size_t o = 0;
    int* hist_t      = (int*)(ws + o); o = align(o + (size_t)NBK * P1 * 4);
    int* colpre_t    = (int*)(ws + o); o = align(o + (size_t)NBK * P1 * 4);
    int* btot        = (int*)(ws + o); o = align(o + (size_t)NBK * 4);
    int* bucket_base = (int*)(ws + o); o = align(o + (size_t)(NBK + 1) * 4);
    int* deg         = (int*)(ws + o); o = align(o + (size_t)n * 4);
    float* dinv      = (float*)(ws + o); o = align(o + (size_t)n * 4);
    int* row_start   = (int*)(ws + o); o = align(o + (size_t)n * 4);
    unsigned int* staging = (unsigned int*)(ws + o); o = align(o + (size_t)E * 4);
    int* csr         = (int*)(ws + o); o = align(o + (size_t)E * 4);
    Half4* g1h       = (Half4*)(ws + o); o = align(o + (size_t)n * 4 * 8);  // 16 halves/node
    Half4* g2h       = (Half4*)(ws + o); o = align(o + (size_t)n * 8);

    const int B = 256;
    int gn4  = (4 * n + B - 1) / B;    // gemm blocks (4 thr/row)
    int gn16 = (16 * n + B - 1) / B;   // gather blocks (16 lanes/node)

    k1a_count<<<P1, B, 0, stream>>>(dst, hist_t, NBK, E);
    kscan1<<<NBK, B, 0, stream>>>(hist_t, colpre_t, btot, NBK);
    kscan2<<<1, B, 0, stream>>>(btot, bucket_base, NBK);
    k1b_fat<<<P1 + gn4, B, 0, stream>>>(src, dst, colpre_t, bucket_base, staging,
                                        x, W1, g1h, NBK, n, E);
    k2_bucket<<<NBK, 512, 0, stream>>>(staging, bucket_base, csr, deg, dinv, row_start,
                                       g1h, n);
    k_gather1<<<gn16, B, 0, stream>>>(g1h, csr, row_start, deg, dinv, b1, W2, g2h, n);
    k_gather2<<<gn16, B, 0, stream>>>(g2h, csr, row_start, deg, dinv, b2, out, n);
}

// Round 10
// 181.986 us; speedup vs baseline: 1.9611x; 1.0045x over previous
//
#include <hip/hip_runtime.h>
#include <hip/hip_fp16.h>
#include <math.h>

// ---------------------------------------------------------------------------
// GCN 2-layer, bucket-partitioned CSR build + wide-parallel fp16 gathers.
//   k1a:    512 edge-slice blocks histogram dst>>9 -> hist_t[bucket][slice]
//   kscan1: per-bucket exclusive scan over slice counts -> colpre_t
//   kscan2: exclusive scan over bucket totals -> bucket_base
//   k1b:    FAT: [scatter packed (src<<9|loc) into bucket-major staging]
//                || [h = x@W1 -> g1h fp16, LDS-staged coalesced]
//   k2:     per-bucket (1024 thr): LDS hist+scan -> deg/dinv/row_start,
//           csr place via LDS tickets, scale g1h by dinv in place
//   gather1: 16 lanes/node, each lane loads a full 32B fp16 message per edge
//            (TWO uint4 loads — a message is 32 B, not 16!), butterfly-reduce,
//            relu/bias + W2 -> g2h
//   gather2: 16 lanes/node edge-split, bias + log_softmax -> out
// ---------------------------------------------------------------------------

#define BSH 9
#define BNODES 512
#define P1 512
#define GROWS 64   // gemm rows per block

struct alignas(8) Half4 { __half x, y, z, w; };

// ---- k1a: per-slice bucket histogram ----
__global__ void k1a_count(const int* __restrict__ dst, int* __restrict__ hist_t,
                          int NBK, int E) {
    __shared__ int lh[256];
    int t = threadIdx.x;
    lh[t] = 0;
    __syncthreads();
    int slice = (E + P1 - 1) / P1;
    int e0 = blockIdx.x * slice, e1 = min(E, e0 + slice);
    for (int e = e0 + t; e < e1; e += 256)
        atomicAdd(&lh[dst[e] >> BSH], 1);
    __syncthreads();
    for (int i = t; i < NBK; i += 256)
        hist_t[(size_t)i * P1 + blockIdx.x] = lh[i];
}

// ---- kscan1: per bucket, exclusive scan over P1 slice counts ----
__global__ void kscan1(const int* __restrict__ hist_t, int* __restrict__ colpre_t,
                       int* __restrict__ btot, int NBK) {
    __shared__ int v[P1], part[256];
    int kb = blockIdx.x, t = threadIdx.x;
    v[t] = hist_t[(size_t)kb * P1 + t];
    v[t + 256] = hist_t[(size_t)kb * P1 + t + 256];
    __syncthreads();
    int a = v[2 * t], c = v[2 * t + 1];
    part[t] = a + c;
    __syncthreads();
    for (int o = 1; o < 256; o <<= 1) {
        int add = (t >= o) ? part[t - o] : 0;
        __syncthreads();
        part[t] += add;
        __syncthreads();
    }
    int pre = (t == 0) ? 0 : part[t - 1];
    colpre_t[(size_t)kb * P1 + 2 * t] = pre;
    colpre_t[(size_t)kb * P1 + 2 * t + 1] = pre + a;
    if (t == 255) btot[kb] = part[255];
}

// ---- kscan2: exclusive scan over bucket totals ----
__global__ void kscan2(const int* __restrict__ btot, int* __restrict__ bucket_base, int NBK) {
    __shared__ int s[256];
    int t = threadIdx.x;
    int orig = (t < NBK) ? btot[t] : 0;
    s[t] = orig;
    __syncthreads();
    for (int o = 1; o < 256; o <<= 1) {
        int add = (t >= o) ? s[t - o] : 0;
        __syncthreads();
        s[t] += add;
        __syncthreads();
    }
    if (t < NBK) {
        bucket_base[t] = s[t] - orig;
        if (t == NBK - 1) bucket_base[NBK] = s[t];
    }
}

// ---- k1b FAT: bucket-major scatter || LDS-staged coalesced gemm1 ----
__global__ void k1b_fat(const int* __restrict__ src, const int* __restrict__ dst,
                        const int* __restrict__ colpre_t, const int* __restrict__ bucket_base,
                        unsigned int* __restrict__ staging,
                        const float* __restrict__ x, const float* __restrict__ W1,
                        Half4* __restrict__ g1h, int NBK, int n, int E) {
    __shared__ float sx[GROWS * 132];   // 33792 B, padded stride 132 (2-way banks)
    __shared__ float4 sW4[512];         // 8192 B: W1 [128][16] as [k][c4]
    int b = blockIdx.x;
    if (b < P1) {
        int* loff = (int*)sx;            // [NBK]
        int* lcur = ((int*)sx) + 1024;   // [NBK]
        for (int i = threadIdx.x; i < NBK; i += 256) {
            loff[i] = bucket_base[i] + colpre_t[(size_t)i * P1 + b];
            lcur[i] = 0;
        }
        __syncthreads();
        int slice = (E + P1 - 1) / P1;
        int e0 = b * slice, e1 = min(E, e0 + slice);
        for (int e = e0 + threadIdx.x; e < e1; e += 256) {
            int d = dst[e], s = src[e];
            int k = d >> BSH;
            int t = atomicAdd(&lcur[k], 1);
            staging[loff[k] + t] = ((unsigned int)s << BSH) | (unsigned int)(d & (BNODES - 1));
        }
    } else {
        int t = threadIdx.x;
        int base = (b - P1) * GROWS;
        // stage W1
        for (int i = t; i < 512; i += 256) sW4[i] = ((const float4*)W1)[i];
        // stage 64 rows of x, fully coalesced
        for (int i = t; i < GROWS * 32; i += 256) {
            int r = i >> 5, c = i & 31;
            int row = base + r;
            float4 v = (row < n) ? ((const float4*)x)[(size_t)row * 32 + c]
                                 : make_float4(0.f, 0.f, 0.f, 0.f);
            *((float4*)&sx[r * 132 + c * 4]) = v;
        }
        __syncthreads();
        int r = t >> 2, c4 = t & 3;
        int row = base + r;
        if (row >= n) return;
        float4 acc = make_float4(0.f, 0.f, 0.f, 0.f);
        #pragma unroll 8
        for (int q = 0; q < 32; ++q) {
            float4 xv = *((const float4*)&sx[r * 132 + q * 4]);
            #pragma unroll
            for (int j = 0; j < 4; ++j) {
                float s = (j == 0) ? xv.x : (j == 1) ? xv.y : (j == 2) ? xv.z : xv.w;
                float4 w = sW4[(q * 4 + j) * 4 + c4];
                acc.x += s * w.x; acc.y += s * w.y; acc.z += s * w.z; acc.w += s * w.w;
            }
        }
        Half4 h;
        h.x = __float2half(acc.x); h.y = __float2half(acc.y);
        h.z = __float2half(acc.z); h.w = __float2half(acc.w);
        g1h[(size_t)row * 4 + c4] = h;   // unscaled; k2 applies dinv
    }
}

// ---- k2: per-bucket CSR + node meta + g1h scaling (1024 threads) ----
__global__ void __launch_bounds__(1024) k2_bucket(
        const unsigned int* __restrict__ staging, const int* __restrict__ bucket_base,
        int* __restrict__ csr, int* __restrict__ deg, float* __restrict__ dinv,
        int* __restrict__ row_start, Half4* __restrict__ g1h, int n) {
    __shared__ int lh[BNODES], sc[BNODES], lcur[BNODES];
    __shared__ float ldv[BNODES];
    int kb = blockIdx.x, t = threadIdx.x;
    int node0 = kb << BSH;
    int nloc = min(BNODES, n - node0);
    int ebase = bucket_base[kb], ecnt = bucket_base[kb + 1] - ebase;
    if (t < BNODES) { lh[t] = 0; lcur[t] = 0; }
    __syncthreads();
    for (int e = t; e < ecnt; e += 1024)
        atomicAdd(&lh[staging[ebase + e] & (BNODES - 1)], 1);
    __syncthreads();
    int own = 0;
    if (t < BNODES) { own = lh[t]; sc[t] = own; }
    __syncthreads();
    for (int o = 1; o < BNODES; o <<= 1) {   // inclusive scan over 512
        int add = 0;
        if (t < BNODES && t >= o) add = sc[t - o];
        __syncthreads();
        if (t < BNODES) sc[t] += add;
        __syncthreads();
    }
    if (t < BNODES) {
        int excl = sc[t] - own;
        if (t < nloc) {
            deg[node0 + t] = own;
            row_start[node0 + t] = ebase + excl;
            float dv = rsqrtf((float)(own + 1));  // +1 self-loop
            dinv[node0 + t] = dv;
            ldv[t] = dv;
        }
        sc[t] = excl;   // reuse as row base for placement
    }
    __syncthreads();
    for (int e = t; e < ecnt; e += 1024) {
        unsigned int p = staging[ebase + e];
        int loc = p & (BNODES - 1);
        int s = (int)(p >> BSH);
        int tk = atomicAdd(&lcur[loc], 1);
        csr[ebase + sc[loc] + tk] = s;
    }
    // scale this bucket's g1h rows by dinv (in place)
    for (int j = t; j < nloc * 4; j += 1024) {
        float dv = ldv[j >> 2];
        Half4 v = g1h[(size_t)node0 * 4 + j];
        v.x = __float2half(__half2float(v.x) * dv);
        v.y = __float2half(__half2float(v.y) * dv);
        v.z = __float2half(__half2float(v.z) * dv);
        v.w = __float2half(__half2float(v.w) * dv);
        g1h[(size_t)node0 * 4 + j] = v;
    }
}

// ---- gather1: 16 lanes/node, full 32B message per lane-edge (2x uint4) ----
__global__ void k_gather1(const uint4* __restrict__ g1q, const int* __restrict__ csr,
                          const int* __restrict__ row_start, const int* __restrict__ deg,
                          const float* __restrict__ dinv, const float* __restrict__ b1,
                          const float* __restrict__ W2, Half4* __restrict__ g2h, int n) {
    int idx = blockIdx.x * 256 + threadIdx.x;
    int i = idx >> 4, l = idx & 15;
    if (i >= n) return;
    int off = row_start[i], dg = deg[i];
    float acc[16];
    #pragma unroll
    for (int j = 0; j < 16; ++j) acc[j] = 0.f;
    if (l == 0) {   // self-loop term: message is 32 B = g1q[2i], g1q[2i+1]
        uint4 p0 = g1q[2 * (size_t)i], p1 = g1q[2 * (size_t)i + 1];
        const __half2* h0 = reinterpret_cast<const __half2*>(&p0);
        const __half2* h1 = reinterpret_cast<const __half2*>(&p1);
        #pragma unroll
        for (int j = 0; j < 4; ++j) {
            float2 f0 = __half22float2(h0[j]);
            float2 f1 = __half22float2(h1[j]);
            acc[2 * j] += f0.x; acc[2 * j + 1] += f0.y;
            acc[8 + 2 * j] += f1.x; acc[9 + 2 * j] += f1.y;
        }
    }
    for (int k = l; k < dg; k += 16) {
        int s = csr[off + k];
        uint4 p0 = g1q[2 * (size_t)s], p1 = g1q[2 * (size_t)s + 1];
        const __half2* h0 = reinterpret_cast<const __half2*>(&p0);
        const __half2* h1 = reinterpret_cast<const __half2*>(&p1);
        #pragma unroll
        for (int j = 0; j < 4; ++j) {
            float2 f0 = __half22float2(h0[j]);
            float2 f1 = __half22float2(h1[j]);
            acc[2 * j] += f0.x; acc[2 * j + 1] += f0.y;
            acc[8 + 2 * j] += f1.x; acc[9 + 2 * j] += f1.y;
        }
    }
    #pragma unroll
    for (int m = 1; m < 16; m <<= 1) {
        #pragma unroll
        for (int j = 0; j < 16; ++j) acc[j] += __shfl_xor(acc[j], m);
    }
    if (l != 0) return;
    float di = dinv[i];
    float o0 = 0.f, o1 = 0.f, o2 = 0.f;
    #pragma unroll
    for (int c = 0; c < 16; ++c) {
        float z = fmaxf(0.f, di * acc[c] + b1[c]);
        o0 += z * W2[c * 3 + 0];
        o1 += z * W2[c * 3 + 1];
        o2 += z * W2[c * 3 + 2];
    }
    Half4 g;
    g.x = __float2half(di * o0); g.y = __float2half(di * o1);
    g.z = __float2half(di * o2); g.w = __float2half(0.f);
    g2h[i] = g;
}

// ---- gather2: 16 lanes/node edge-split, bias + log_softmax -> out ----
__global__ void k_gather2(const Half4* __restrict__ g2h, const int* __restrict__ csr,
                          const int* __restrict__ row_start, const int* __restrict__ deg,
                          const float* __restrict__ dinv, const float* __restrict__ b2,
                          float* __restrict__ out, int n) {
    int idx = blockIdx.x * 256 + threadIdx.x;
    int i = idx >> 4, l = idx & 15;
    if (i >= n) return;
    int off = row_start[i], dg = deg[i];
    float v0 = 0.f, v1 = 0.f, v2 = 0.f;
    if (l == 0) {
        Half4 s = g2h[i];
        v0 = __half2float(s.x); v1 = __half2float(s.y); v2 = __half2float(s.z);
    }
    for (int e = l; e < dg; e += 16) {
        int s = csr[off + e];
        Half4 g = g2h[s];
        v0 += __half2float(g.x); v1 += __half2float(g.y); v2 += __half2float(g.z);
    }
    #pragma unroll
    for (int o = 1; o < 16; o <<= 1) {
        v0 += __shfl_xor(v0, o);
        v1 += __shfl_xor(v1, o);
        v2 += __shfl_xor(v2, o);
    }
    if (l >= 3) return;
    float di = dinv[i];
    float a0 = di * v0 + b2[0];
    float a1 = di * v1 + b2[1];
    float a2 = di * v2 + b2[2];
    float m = fmaxf(a0, fmaxf(a1, a2));
    float lse = logf(expf(a0 - m) + expf(a1 - m) + expf(a2 - m));
    float r = (l == 0) ? a0 : (l == 1) ? a1 : a2;
    out[(size_t)i * 3 + l] = r - m - lse;
}

// ======================== launch ========================
extern "C" void kernel_launch(void* const* d_in, const int* in_sizes, int n_in,
                              void* d_out, int out_size, void* d_ws, size_t ws_size,
                              hipStream_t stream) {
    const float* x  = (const float*)d_in[0];
    const int*   ei = (const int*)d_in[1];      // [2][E]
    const float* W1 = (const float*)d_in[2];    // [128][16]
    const float* b1 = (const float*)d_in[3];    // [16]
    const float* W2 = (const float*)d_in[4];    // [16][3]
    const float* b2 = (const float*)d_in[5];    // [3]
    float* out = (float*)d_out;

    const int n = in_sizes[0] / 128;   // 100000
    const int E = in_sizes[1] / 2;     // 1600000
    const int* src = ei;
    const int* dst = ei + E;

    const int NBK = (n + BNODES - 1) >> BSH;   // 196

    auto align = [](size_t v) { return (v + 255) & ~(size_t)255; };
    char* ws = (char*)d_ws;
    size_t o = 0;
    int* hist_t      = (int*)(ws + o); o = align(o + (size_t)NBK * P1 * 4);
    int* colpre_t    = (int*)(ws + o); o = align(o + (size_t)NBK * P1 * 4);
    int* btot        = (int*)(ws + o); o = align(o + (size_t)NBK * 4);
    int* bucket_base = (int*)(ws + o); o = align(o + (size_t)(NBK + 1) * 4);
    int* deg         = (int*)(ws + o); o = align(o + (size_t)n * 4);
    float* dinv      = (float*)(ws + o); o = align(o + (size_t)n * 4);
    int* row_start   = (int*)(ws + o); o = align(o + (size_t)n * 4);
    unsigned int* staging = (unsigned int*)(ws + o); o = align(o + (size_t)E * 4);
    int* csr         = (int*)(ws + o); o = align(o + (size_t)E * 4);
    Half4* g1h       = (Half4*)(ws + o); o = align(o + (size_t)n * 4 * 8);  // 16 halves/node
    Half4* g2h       = (Half4*)(ws + o); o = align(o + (size_t)n * 8);

    const int B = 256;
    int gGemm = (n + GROWS - 1) / GROWS;   // 1563
    int gn16  = (16 * n + B - 1) / B;      // 6250

    k1a_count<<<P1, B, 0, stream>>>(dst, hist_t, NBK, E);
    kscan1<<<NBK, B, 0, stream>>>(hist_t, colpre_t, btot, NBK);
    kscan2<<<1, B, 0, stream>>>(btot, bucket_base, NBK);
    k1b_fat<<<P1 + gGemm, B, 0, stream>>>(src, dst, colpre_t, bucket_base, staging,
                                          x, W1, g1h, NBK, n, E);
    k2_bucket<<<NBK, 1024, 0, stream>>>(staging, bucket_base, csr, deg, dinv, row_start,
                                        g1h, n);
    k_gather1<<<gn16, B, 0, stream>>>((const uint4*)g1h, csr, row_start, deg, dinv, b1, W2,
                                      g2h, n);
    k_gather2<<<gn16, B, 0, stream>>>(g2h, csr, row_start, deg, dinv, b2, out, n);
}

// Round 11
// 171.182 us; speedup vs baseline: 2.0849x; 1.0631x over previous
//
#include <hip/hip_runtime.h>
#include <hip/hip_fp16.h>
#include <math.h>

// ---------------------------------------------------------------------------
// GCN 2-layer, bucket-partitioned CSR build + wide-parallel fp16 gathers.
// R11: both scatter phases (staging write in k1b, csr place in k2) are
// LDS-sorted first, then written with lane-contiguous (coalesced) stores —
// scattered 4B store transactions are txn-rate-bound (~40 G/s ceiling,
// evidence R2/R3/R6/R8: immune to parallelism).
// ---------------------------------------------------------------------------

#define BSH 9
#define BNODES 512
#define P1 512
#define GROWS 64    // gemm rows per block
#define K2BUF 10240 // k2 LDS sort buffer entries (bucket mean 8192, sd ~90)

struct alignas(8) Half4 { __half x, y, z, w; };

// ---- k1a: per-slice bucket histogram ----
__global__ void k1a_count(const int* __restrict__ dst, int* __restrict__ hist_t,
                          int NBK, int E) {
    __shared__ int lh[256];
    int t = threadIdx.x;
    lh[t] = 0;
    __syncthreads();
    int slice = (E + P1 - 1) / P1;
    int e0 = blockIdx.x * slice, e1 = min(E, e0 + slice);
    for (int e = e0 + t; e < e1; e += 256)
        atomicAdd(&lh[dst[e] >> BSH], 1);
    __syncthreads();
    for (int i = t; i < NBK; i += 256)
        hist_t[(size_t)i * P1 + blockIdx.x] = lh[i];
}

// ---- kscan1: per bucket, exclusive scan over P1 slice counts ----
__global__ void kscan1(const int* __restrict__ hist_t, int* __restrict__ colpre_t,
                       int* __restrict__ btot, int NBK) {
    __shared__ int v[P1], part[256];
    int kb = blockIdx.x, t = threadIdx.x;
    v[t] = hist_t[(size_t)kb * P1 + t];
    v[t + 256] = hist_t[(size_t)kb * P1 + t + 256];
    __syncthreads();
    int a = v[2 * t], c = v[2 * t + 1];
    part[t] = a + c;
    __syncthreads();
    for (int o = 1; o < 256; o <<= 1) {
        int add = (t >= o) ? part[t - o] : 0;
        __syncthreads();
        part[t] += add;
        __syncthreads();
    }
    int pre = (t == 0) ? 0 : part[t - 1];
    colpre_t[(size_t)kb * P1 + 2 * t] = pre;
    colpre_t[(size_t)kb * P1 + 2 * t + 1] = pre + a;
    if (t == 255) btot[kb] = part[255];
}

// ---- kscan2: exclusive scan over bucket totals ----
__global__ void kscan2(const int* __restrict__ btot, int* __restrict__ bucket_base, int NBK) {
    __shared__ int s[256];
    int t = threadIdx.x;
    int orig = (t < NBK) ? btot[t] : 0;
    s[t] = orig;
    __syncthreads();
    for (int o = 1; o < 256; o <<= 1) {
        int add = (t >= o) ? s[t - o] : 0;
        __syncthreads();
        s[t] += add;
        __syncthreads();
    }
    if (t < NBK) {
        bucket_base[t] = s[t] - orig;
        if (t == NBK - 1) bucket_base[NBK] = s[t];
    }
}

// ---- k1b FAT: [LDS-sorted bucket scatter] || [LDS-staged coalesced gemm1] ----
__global__ void k1b_fat(const int* __restrict__ src, const int* __restrict__ dst,
                        const int* __restrict__ colpre_t, const int* __restrict__ bucket_base,
                        unsigned int* __restrict__ staging,
                        const float* __restrict__ x, const float* __restrict__ W1,
                        Half4* __restrict__ g1h, int NBK, int n, int E) {
    __shared__ float sx[GROWS * 132];   // 33792 B; scatter branch aliases as int[]
    __shared__ float4 sW4[512];         // 8192 B: W1 [128][16] as [k][c4]
    int b = blockIdx.x;
    if (b < P1) {
        // layout inside sx (8448 ints): hist | cs | loff | cur | buf | gaddr
        int* hist  = (int*)sx;          // [256]
        int* cs    = hist + 256;        // [256] chunk-local bucket starts
        int* loff  = hist + 512;        // [256] absolute run starts
        int* cur   = hist + 768;        // [256] fresh tickets
        int* buf   = hist + 1024;       // [3200] sorted packed values
        int* gaddr = buf + 3200;        // [3200] sorted global addresses
        int t = threadIdx.x;
        hist[t] = 0; cur[t] = 0;
        for (int i = t; i < NBK; i += 256)
            loff[i] = bucket_base[i] + colpre_t[(size_t)i * P1 + b];
        __syncthreads();
        int slice = (E + P1 - 1) / P1;
        int e0 = b * slice, e1 = min(E, e0 + slice);
        int len = e1 - e0;
        // pass A: histogram
        for (int e = e0 + t; e < e1; e += 256)
            atomicAdd(&hist[dst[e] >> BSH], 1);
        __syncthreads();
        // exclusive scan hist[0..256) -> cs
        int h = hist[t];
        cs[t] = h;
        __syncthreads();
        for (int o = 1; o < 256; o <<= 1) {
            int add = (t >= o) ? cs[t - o] : 0;
            __syncthreads();
            cs[t] += add;
            __syncthreads();
        }
        int incl = cs[t];
        __syncthreads();
        cs[t] = incl - h;  // exclusive
        __syncthreads();
        // pass B: fresh tickets, place into LDS in bucket-sorted order
        for (int e = e0 + t; e < e1; e += 256) {
            int d = dst[e], s = src[e];
            int k = d >> BSH;
            int tk = atomicAdd(&cur[k], 1);
            int pos = cs[k] + tk;
            buf[pos] = (s << BSH) | (d & (BNODES - 1));
            gaddr[pos] = loff[k] + tk;
        }
        __syncthreads();
        // coalesced copy-out: consecutive lanes -> consecutive run addresses
        for (int p = t; p < len; p += 256)
            staging[gaddr[p]] = (unsigned int)buf[p];
    } else {
        int t = threadIdx.x;
        int base = (b - P1) * GROWS;
        for (int i = t; i < 512; i += 256) sW4[i] = ((const float4*)W1)[i];
        for (int i = t; i < GROWS * 32; i += 256) {
            int r = i >> 5, c = i & 31;
            int row = base + r;
            float4 v = (row < n) ? ((const float4*)x)[(size_t)row * 32 + c]
                                 : make_float4(0.f, 0.f, 0.f, 0.f);
            *((float4*)&sx[r * 132 + c * 4]) = v;
        }
        __syncthreads();
        int r = t >> 2, c4 = t & 3;
        int row = base + r;
        if (row >= n) return;
        float4 acc = make_float4(0.f, 0.f, 0.f, 0.f);
        #pragma unroll 8
        for (int q = 0; q < 32; ++q) {
            float4 xv = *((const float4*)&sx[r * 132 + q * 4]);
            #pragma unroll
            for (int j = 0; j < 4; ++j) {
                float s = (j == 0) ? xv.x : (j == 1) ? xv.y : (j == 2) ? xv.z : xv.w;
                float4 w = sW4[(q * 4 + j) * 4 + c4];
                acc.x += s * w.x; acc.y += s * w.y; acc.z += s * w.z; acc.w += s * w.w;
            }
        }
        Half4 hh;
        hh.x = __float2half(acc.x); hh.y = __float2half(acc.y);
        hh.z = __float2half(acc.z); hh.w = __float2half(acc.w);
        g1h[(size_t)row * 4 + c4] = hh;   // unscaled; k2 applies dinv
    }
}

// ---- k2: per-bucket CSR (LDS-sorted, contiguous write-out) + meta + scale ----
__global__ void __launch_bounds__(1024) k2_bucket(
        const unsigned int* __restrict__ staging, const int* __restrict__ bucket_base,
        int* __restrict__ csr, int* __restrict__ deg, float* __restrict__ dinv,
        int* __restrict__ row_start, Half4* __restrict__ g1h, int n) {
    __shared__ int lh[BNODES], sc[BNODES], lcur[BNODES];
    __shared__ float ldv[BNODES];
    __shared__ int buf[K2BUF];          // 40960 B sorted srcs
    int kb = blockIdx.x, t = threadIdx.x;
    int node0 = kb << BSH;
    int nloc = min(BNODES, n - node0);
    int ebase = bucket_base[kb], ecnt = bucket_base[kb + 1] - ebase;
    if (t < BNODES) { lh[t] = 0; lcur[t] = 0; }
    __syncthreads();
    for (int e = t; e < ecnt; e += 1024)
        atomicAdd(&lh[staging[ebase + e] & (BNODES - 1)], 1);
    __syncthreads();
    int own = 0;
    if (t < BNODES) { own = lh[t]; sc[t] = own; }
    __syncthreads();
    for (int o = 1; o < BNODES; o <<= 1) {   // inclusive scan over 512
        int add = 0;
        if (t < BNODES && t >= o) add = sc[t - o];
        __syncthreads();
        if (t < BNODES) sc[t] += add;
        __syncthreads();
    }
    if (t < BNODES) {
        int excl = sc[t] - own;
        if (t < nloc) {
            deg[node0 + t] = own;
            row_start[node0 + t] = ebase + excl;
            float dv = rsqrtf((float)(own + 1));  // +1 self-loop
            dinv[node0 + t] = dv;
            ldv[t] = dv;
        }
        sc[t] = excl;   // reuse as row base for placement
    }
    __syncthreads();
    if (ecnt <= K2BUF) {
        // sort into LDS, then perfectly-contiguous copy-out
        for (int e = t; e < ecnt; e += 1024) {
            unsigned int p = staging[ebase + e];
            int loc = p & (BNODES - 1);
            int tk = atomicAdd(&lcur[loc], 1);
            buf[sc[loc] + tk] = (int)(p >> BSH);
        }
        __syncthreads();
        for (int p = t; p < ecnt; p += 1024)
            csr[ebase + p] = buf[p];
    } else {
        // safety fallback (statistically unreachable): direct scattered place
        for (int e = t; e < ecnt; e += 1024) {
            unsigned int p = staging[ebase + e];
            int loc = p & (BNODES - 1);
            int tk = atomicAdd(&lcur[loc], 1);
            csr[ebase + sc[loc] + tk] = (int)(p >> BSH);
        }
    }
    // scale this bucket's g1h rows by dinv (in place)
    for (int j = t; j < nloc * 4; j += 1024) {
        float dv = ldv[j >> 2];
        Half4 v = g1h[(size_t)node0 * 4 + j];
        v.x = __float2half(__half2float(v.x) * dv);
        v.y = __float2half(__half2float(v.y) * dv);
        v.z = __float2half(__half2float(v.z) * dv);
        v.w = __float2half(__half2float(v.w) * dv);
        g1h[(size_t)node0 * 4 + j] = v;
    }
}

// ---- gather1: 16 lanes/node, full 32B message per lane-edge (2x uint4) ----
__global__ void k_gather1(const uint4* __restrict__ g1q, const int* __restrict__ csr,
                          const int* __restrict__ row_start, const int* __restrict__ deg,
                          const float* __restrict__ dinv, const float* __restrict__ b1,
                          const float* __restrict__ W2, Half4* __restrict__ g2h, int n) {
    int idx = blockIdx.x * 256 + threadIdx.x;
    int i = idx >> 4, l = idx & 15;
    if (i >= n) return;
    int off = row_start[i], dg = deg[i];
    float acc[16];
    #pragma unroll
    for (int j = 0; j < 16; ++j) acc[j] = 0.f;
    if (l == 0) {   // self-loop term: message is 32 B = g1q[2i], g1q[2i+1]
        uint4 p0 = g1q[2 * (size_t)i], p1 = g1q[2 * (size_t)i + 1];
        const __half2* h0 = reinterpret_cast<const __half2*>(&p0);
        const __half2* h1 = reinterpret_cast<const __half2*>(&p1);
        #pragma unroll
        for (int j = 0; j < 4; ++j) {
            float2 f0 = __half22float2(h0[j]);
            float2 f1 = __half22float2(h1[j]);
            acc[2 * j] += f0.x; acc[2 * j + 1] += f0.y;
            acc[8 + 2 * j] += f1.x; acc[9 + 2 * j] += f1.y;
        }
    }
    for (int k = l; k < dg; k += 16) {
        int s = csr[off + k];
        uint4 p0 = g1q[2 * (size_t)s], p1 = g1q[2 * (size_t)s + 1];
        const __half2* h0 = reinterpret_cast<const __half2*>(&p0);
        const __half2* h1 = reinterpret_cast<const __half2*>(&p1);
        #pragma unroll
        for (int j = 0; j < 4; ++j) {
            float2 f0 = __half22float2(h0[j]);
            float2 f1 = __half22float2(h1[j]);
            acc[2 * j] += f0.x; acc[2 * j + 1] += f0.y;
            acc[8 + 2 * j] += f1.x; acc[9 + 2 * j] += f1.y;
        }
    }
    #pragma unroll
    for (int m = 1; m < 16; m <<= 1) {
        #pragma unroll
        for (int j = 0; j < 16; ++j) acc[j] += __shfl_xor(acc[j], m);
    }
    if (l != 0) return;
    float di = dinv[i];
    float o0 = 0.f, o1 = 0.f, o2 = 0.f;
    #pragma unroll
    for (int c = 0; c < 16; ++c) {
        float z = fmaxf(0.f, di * acc[c] + b1[c]);
        o0 += z * W2[c * 3 + 0];
        o1 += z * W2[c * 3 + 1];
        o2 += z * W2[c * 3 + 2];
    }
    Half4 g;
    g.x = __float2half(di * o0); g.y = __float2half(di * o1);
    g.z = __float2half(di * o2); g.w = __float2half(0.f);
    g2h[i] = g;
}

// ---- gather2: 16 lanes/node edge-split, bias + log_softmax -> out ----
__global__ void k_gather2(const Half4* __restrict__ g2h, const int* __restrict__ csr,
                          const int* __restrict__ row_start, const int* __restrict__ deg,
                          const float* __restrict__ dinv, const float* __restrict__ b2,
                          float* __restrict__ out, int n) {
    int idx = blockIdx.x * 256 + threadIdx.x;
    int i = idx >> 4, l = idx & 15;
    if (i >= n) return;
    int off = row_start[i], dg = deg[i];
    float v0 = 0.f, v1 = 0.f, v2 = 0.f;
    if (l == 0) {
        Half4 s = g2h[i];
        v0 = __half2float(s.x); v1 = __half2float(s.y); v2 = __half2float(s.z);
    }
    for (int e = l; e < dg; e += 16) {
        int s = csr[off + e];
        Half4 g = g2h[s];
        v0 += __half2float(g.x); v1 += __half2float(g.y); v2 += __half2float(g.z);
    }
    #pragma unroll
    for (int o = 1; o < 16; o <<= 1) {
        v0 += __shfl_xor(v0, o);
        v1 += __shfl_xor(v1, o);
        v2 += __shfl_xor(v2, o);
    }
    if (l >= 3) return;
    float di = dinv[i];
    float a0 = di * v0 + b2[0];
    float a1 = di * v1 + b2[1];
    float a2 = di * v2 + b2[2];
    float m = fmaxf(a0, fmaxf(a1, a2));
    float lse = logf(expf(a0 - m) + expf(a1 - m) + expf(a2 - m));
    float r = (l == 0) ? a0 : (l == 1) ? a1 : a2;
    out[(size_t)i * 3 + l] = r - m - lse;
}

// ======================== launch ========================
extern "C" void kernel_launch(void* const* d_in, const int* in_sizes, int n_in,
                              void* d_out, int out_size, void* d_ws, size_t ws_size,
                              hipStream_t stream) {
    const float* x  = (const float*)d_in[0];
    const int*   ei = (const int*)d_in[1];      // [2][E]
    const float* W1 = (const float*)d_in[2];    // [128][16]
    const float* b1 = (const float*)d_in[3];    // [16]
    const float* W2 = (const float*)d_in[4];    // [16][3]
    const float* b2 = (const float*)d_in[5];    // [3]
    float* out = (float*)d_out;

    const int n = in_sizes[0] / 128;   // 100000
    const int E = in_sizes[1] / 2;     // 1600000
    const int* src = ei;
    const int* dst = ei + E;

    const int NBK = (n + BNODES - 1) >> BSH;   // 196

    auto align = [](size_t v) { return (v + 255) & ~(size_t)255; };
    char* ws = (char*)d_ws;
    size_t o = 0;
    int* hist_t      = (int*)(ws + o); o = align(o + (size_t)NBK * P1 * 4);
    int* colpre_t    = (int*)(ws + o); o = align(o + (size_t)NBK * P1 * 4);
    int* btot        = (int*)(ws + o); o = align(o + (size_t)NBK * 4);
    int* bucket_base = (int*)(ws + o); o = align(o + (size_t)(NBK + 1) * 4);
    int* deg         = (int*)(ws + o); o = align(o + (size_t)n * 4);
    float* dinv      = (float*)(ws + o); o = align(o + (size_t)n * 4);
    int* row_start   = (int*)(ws + o); o = align(o + (size_t)n * 4);
    unsigned int* staging = (unsigned int*)(ws + o); o = align(o + (size_t)E * 4);
    int* csr         = (int*)(ws + o); o = align(o + (size_t)E * 4);
    Half4* g1h       = (Half4*)(ws + o); o = align(o + (size_t)n * 4 * 8);  // 16 halves/node
    Half4* g2h       = (Half4*)(ws + o); o = align(o + (size_t)n * 8);

    const int B = 256;
    int gGemm = (n + GROWS - 1) / GROWS;   // 1563
    int gn16  = (16 * n + B - 1) / B;      // 6250

    k1a_count<<<P1, B, 0, stream>>>(dst, hist_t, NBK, E);
    kscan1<<<NBK, B, 0, stream>>>(hist_t, colpre_t, btot, NBK);
    kscan2<<<1, B, 0, stream>>>(btot, bucket_base, NBK);
    k1b_fat<<<P1 + gGemm, B, 0, stream>>>(src, dst, colpre_t, bucket_base, staging,
                                          x, W1, g1h, NBK, n, E);
    k2_bucket<<<NBK, 1024, 0, stream>>>(staging, bucket_base, csr, deg, dinv, row_start,
                                        g1h, n);
    k_gather1<<<gn16, B, 0, stream>>>((const uint4*)g1h, csr, row_start, deg, dinv, b1, W2,
                                      g2h, n);
    k_gather2<<<gn16, B, 0, stream>>>(g2h, csr, row_start, deg, dinv, b2, out, n);
}

// Round 12
// 164.630 us; speedup vs baseline: 2.1678x; 1.0398x over previous
//
#include <hip/hip_runtime.h>
#include <hip/hip_fp16.h>
#include <math.h>

// ---------------------------------------------------------------------------
// GCN 2-layer, bucket-partitioned CSR build + wide-parallel fp16 gathers.
// R12: fixed per-bucket capacity BCAP (kills kscan2), register-cached edge
// slice in k1b (single global read), tree-halving reduction in gather1.
// ---------------------------------------------------------------------------

#define BSH 9
#define BNODES 512
#define P1 512
#define GROWS 64     // gemm rows per block
#define K2BUF 10240  // k2 LDS sort buffer entries
#define BCAP 12288   // per-bucket staging/csr capacity (mean 8163, +45 sigma)
#define EPT 16       // max edges per thread in k1b register cache

struct alignas(8) Half4 { __half x, y, z, w; };

// ---- k1a: per-slice bucket histogram ----
__global__ void k1a_count(const int* __restrict__ dst, int* __restrict__ hist_t,
                          int NBK, int E) {
    __shared__ int lh[256];
    int t = threadIdx.x;
    lh[t] = 0;
    __syncthreads();
    int slice = (E + P1 - 1) / P1;
    int e0 = blockIdx.x * slice, e1 = min(E, e0 + slice);
    for (int e = e0 + t; e < e1; e += 256)
        atomicAdd(&lh[dst[e] >> BSH], 1);
    __syncthreads();
    for (int i = t; i < NBK; i += 256)
        hist_t[(size_t)i * P1 + blockIdx.x] = lh[i];
}

// ---- kscan1: per bucket, exclusive scan over P1 slice counts; btot out ----
__global__ void kscan1(const int* __restrict__ hist_t, int* __restrict__ colpre_t,
                       int* __restrict__ btot, int NBK) {
    __shared__ int v[P1], part[256];
    int kb = blockIdx.x, t = threadIdx.x;
    v[t] = hist_t[(size_t)kb * P1 + t];
    v[t + 256] = hist_t[(size_t)kb * P1 + t + 256];
    __syncthreads();
    int a = v[2 * t], c = v[2 * t + 1];
    part[t] = a + c;
    __syncthreads();
    for (int o = 1; o < 256; o <<= 1) {
        int add = (t >= o) ? part[t - o] : 0;
        __syncthreads();
        part[t] += add;
        __syncthreads();
    }
    int pre = (t == 0) ? 0 : part[t - 1];
    colpre_t[(size_t)kb * P1 + 2 * t] = pre;
    colpre_t[(size_t)kb * P1 + 2 * t + 1] = pre + a;
    if (t == 255) btot[kb] = part[255];
}

// ---- k1b FAT: [reg-cached LDS-sorted scatter] || [LDS-staged gemm1] ----
__global__ void k1b_fat(const int* __restrict__ src, const int* __restrict__ dst,
                        const int* __restrict__ colpre_t,
                        unsigned int* __restrict__ staging,
                        const float* __restrict__ x, const float* __restrict__ W1,
                        Half4* __restrict__ g1h, int NBK, int n, int E) {
    __shared__ float sx[GROWS * 132];   // 33792 B; scatter branch aliases as int[]
    __shared__ float4 sW4[512];         // 8192 B: W1 [128][16] as [k][c4]
    int b = blockIdx.x;
    if (b < P1) {
        // layout in sx (8448 ints): hist | cs | loff | cur | buf | gaddr
        int* hist  = (int*)sx;          // [256]
        int* cs    = hist + 256;        // [256]
        int* loff  = hist + 512;        // [256] absolute run starts
        int* cur   = hist + 768;        // [256]
        int* buf   = hist + 1024;       // [3200]
        int* gaddr = buf + 3200;        // [3200]
        int t = threadIdx.x;
        hist[t] = 0; cur[t] = 0;
        for (int i = t; i < NBK; i += 256)
            loff[i] = i * BCAP + colpre_t[(size_t)i * P1 + b];
        __syncthreads();
        int slice = (E + P1 - 1) / P1;
        int e0 = b * slice, e1 = min(E, e0 + slice);
        int len = e1 - e0;
        // single global read into registers
        int dl[EPT], sl[EPT];
        int cnt = 0;
        for (int e = e0 + t; e < e1 && cnt < EPT; e += 256, ++cnt) {
            dl[cnt] = dst[e];
            sl[cnt] = src[e];
        }
        // pass A: histogram from registers
        for (int i = 0; i < cnt; ++i)
            atomicAdd(&hist[dl[i] >> BSH], 1);
        __syncthreads();
        // exclusive scan hist[0..256) -> cs
        int h = hist[t];
        cs[t] = h;
        __syncthreads();
        for (int o = 1; o < 256; o <<= 1) {
            int add = (t >= o) ? cs[t - o] : 0;
            __syncthreads();
            cs[t] += add;
            __syncthreads();
        }
        int incl = cs[t];
        __syncthreads();
        cs[t] = incl - h;  // exclusive
        __syncthreads();
        // pass B: place into LDS bucket-sorted
        for (int i = 0; i < cnt; ++i) {
            int d = dl[i], s = sl[i];
            int k = d >> BSH;
            int tk = atomicAdd(&cur[k], 1);
            int pos = cs[k] + tk;
            buf[pos] = (s << BSH) | (d & (BNODES - 1));
            gaddr[pos] = loff[k] + tk;
        }
        __syncthreads();
        // coalesced copy-out
        for (int p = t; p < len; p += 256)
            staging[gaddr[p]] = (unsigned int)buf[p];
    } else {
        int t = threadIdx.x;
        int base = (b - P1) * GROWS;
        for (int i = t; i < 512; i += 256) sW4[i] = ((const float4*)W1)[i];
        for (int i = t; i < GROWS * 32; i += 256) {
            int r = i >> 5, c = i & 31;
            int row = base + r;
            float4 v = (row < n) ? ((const float4*)x)[(size_t)row * 32 + c]
                                 : make_float4(0.f, 0.f, 0.f, 0.f);
            *((float4*)&sx[r * 132 + c * 4]) = v;
        }
        __syncthreads();
        int r = t >> 2, c4 = t & 3;
        int row = base + r;
        if (row >= n) return;
        float4 acc = make_float4(0.f, 0.f, 0.f, 0.f);
        #pragma unroll 8
        for (int q = 0; q < 32; ++q) {
            float4 xv = *((const float4*)&sx[r * 132 + q * 4]);
            #pragma unroll
            for (int j = 0; j < 4; ++j) {
                float s = (j == 0) ? xv.x : (j == 1) ? xv.y : (j == 2) ? xv.z : xv.w;
                float4 w = sW4[(q * 4 + j) * 4 + c4];
                acc.x += s * w.x; acc.y += s * w.y; acc.z += s * w.z; acc.w += s * w.w;
            }
        }
        Half4 hh;
        hh.x = __float2half(acc.x); hh.y = __float2half(acc.y);
        hh.z = __float2half(acc.z); hh.w = __float2half(acc.w);
        g1h[(size_t)row * 4 + c4] = hh;   // unscaled; k2 applies dinv
    }
}

// ---- k2: per-bucket CSR (LDS-sorted, contiguous write-out) + meta + scale ----
__global__ void __launch_bounds__(1024) k2_bucket(
        const unsigned int* __restrict__ staging, const int* __restrict__ btot,
        int* __restrict__ csr, int* __restrict__ deg, float* __restrict__ dinv,
        int* __restrict__ row_start, Half4* __restrict__ g1h, int n) {
    __shared__ int lh[BNODES], sc[BNODES], lcur[BNODES];
    __shared__ float ldv[BNODES];
    __shared__ int buf[K2BUF];
    int kb = blockIdx.x, t = threadIdx.x;
    int node0 = kb << BSH;
    int nloc = min(BNODES, n - node0);
    int ebase = kb * BCAP;
    int ecnt = btot[kb];
    if (t < BNODES) { lh[t] = 0; lcur[t] = 0; }
    __syncthreads();
    for (int e = t; e < ecnt; e += 1024)
        atomicAdd(&lh[staging[ebase + e] & (BNODES - 1)], 1);
    __syncthreads();
    int own = 0;
    if (t < BNODES) { own = lh[t]; sc[t] = own; }
    __syncthreads();
    for (int o = 1; o < BNODES; o <<= 1) {   // inclusive scan over 512
        int add = 0;
        if (t < BNODES && t >= o) add = sc[t - o];
        __syncthreads();
        if (t < BNODES) sc[t] += add;
        __syncthreads();
    }
    if (t < BNODES) {
        int excl = sc[t] - own;
        if (t < nloc) {
            deg[node0 + t] = own;
            row_start[node0 + t] = ebase + excl;
            float dv = rsqrtf((float)(own + 1));  // +1 self-loop
            dinv[node0 + t] = dv;
            ldv[t] = dv;
        }
        sc[t] = excl;
    }
    __syncthreads();
    if (ecnt <= K2BUF) {
        for (int e = t; e < ecnt; e += 1024) {
            unsigned int p = staging[ebase + e];
            int loc = p & (BNODES - 1);
            int tk = atomicAdd(&lcur[loc], 1);
            buf[sc[loc] + tk] = (int)(p >> BSH);
        }
        __syncthreads();
        for (int p = t; p < ecnt; p += 1024)
            csr[ebase + p] = buf[p];
    } else {
        for (int e = t; e < ecnt; e += 1024) {
            unsigned int p = staging[ebase + e];
            int loc = p & (BNODES - 1);
            int tk = atomicAdd(&lcur[loc], 1);
            csr[ebase + sc[loc] + tk] = (int)(p >> BSH);
        }
    }
    for (int j = t; j < nloc * 4; j += 1024) {
        float dv = ldv[j >> 2];
        Half4 v = g1h[(size_t)node0 * 4 + j];
        v.x = __float2half(__half2float(v.x) * dv);
        v.y = __float2half(__half2float(v.y) * dv);
        v.z = __float2half(__half2float(v.z) * dv);
        v.w = __float2half(__half2float(v.w) * dv);
        g1h[(size_t)node0 * 4 + j] = v;
    }
}

// ---- gather1: 16 lanes/node, 32B msg per lane-edge, tree-halving reduce ----
__global__ void k_gather1(const uint4* __restrict__ g1q, const int* __restrict__ csr,
                          const int* __restrict__ row_start, const int* __restrict__ deg,
                          const float* __restrict__ dinv, const float* __restrict__ b1,
                          const float* __restrict__ W2, Half4* __restrict__ g2h, int n) {
    int idx = blockIdx.x * 256 + threadIdx.x;
    int i = idx >> 4, l = idx & 15;
    if (i >= n) return;
    int off = row_start[i], dg = deg[i];
    float acc[16];
    #pragma unroll
    for (int j = 0; j < 16; ++j) acc[j] = 0.f;
    if (l == 0) {   // self-loop term (32 B = g1q[2i], g1q[2i+1])
        uint4 p0 = g1q[2 * (size_t)i], p1 = g1q[2 * (size_t)i + 1];
        const __half2* h0 = reinterpret_cast<const __half2*>(&p0);
        const __half2* h1 = reinterpret_cast<const __half2*>(&p1);
        #pragma unroll
        for (int j = 0; j < 4; ++j) {
            float2 f0 = __half22float2(h0[j]);
            float2 f1 = __half22float2(h1[j]);
            acc[2 * j] += f0.x; acc[2 * j + 1] += f0.y;
            acc[8 + 2 * j] += f1.x; acc[9 + 2 * j] += f1.y;
        }
    }
    for (int k = l; k < dg; k += 16) {
        int s = csr[off + k];
        uint4 p0 = g1q[2 * (size_t)s], p1 = g1q[2 * (size_t)s + 1];
        const __half2* h0 = reinterpret_cast<const __half2*>(&p0);
        const __half2* h1 = reinterpret_cast<const __half2*>(&p1);
        #pragma unroll
        for (int j = 0; j < 4; ++j) {
            float2 f0 = __half22float2(h0[j]);
            float2 f1 = __half22float2(h1[j]);
            acc[2 * j] += f0.x; acc[2 * j + 1] += f0.y;
            acc[8 + 2 * j] += f1.x; acc[9 + 2 * j] += f1.y;
        }
    }
    // tree-halving cross-lane reduce: after step k, acc[0..(8>>k)) hold sums
    #pragma unroll
    for (int j = 0; j < 8; ++j) {
        float send = (l & 1) ? acc[j] : acc[j + 8];
        float recv = __shfl_xor(send, 1);
        acc[j] = ((l & 1) ? acc[j + 8] : acc[j]) + recv;
    }
    #pragma unroll
    for (int j = 0; j < 4; ++j) {
        float send = (l & 2) ? acc[j] : acc[j + 4];
        float recv = __shfl_xor(send, 2);
        acc[j] = ((l & 2) ? acc[j + 4] : acc[j]) + recv;
    }
    #pragma unroll
    for (int j = 0; j < 2; ++j) {
        float send = (l & 4) ? acc[j] : acc[j + 2];
        float recv = __shfl_xor(send, 4);
        acc[j] = ((l & 4) ? acc[j + 2] : acc[j]) + recv;
    }
    {
        float send = (l & 8) ? acc[0] : acc[1];
        float recv = __shfl_xor(send, 8);
        acc[0] = ((l & 8) ? acc[1] : acc[0]) + recv;
    }
    // lane l now holds feature f = bit-reverse-4(l)
    int f = ((l & 1) << 3) | ((l & 2) << 1) | ((l & 4) >> 1) | ((l & 8) >> 3);
    float di = dinv[i];
    float z = fmaxf(0.f, di * acc[0] + b1[f]);
    float o0 = z * W2[f * 3 + 0];
    float o1 = z * W2[f * 3 + 1];
    float o2 = z * W2[f * 3 + 2];
    #pragma unroll
    for (int m = 1; m < 16; m <<= 1) {
        o0 += __shfl_xor(o0, m);
        o1 += __shfl_xor(o1, m);
        o2 += __shfl_xor(o2, m);
    }
    if (l != 0) return;
    Half4 g;
    g.x = __float2half(di * o0); g.y = __float2half(di * o1);
    g.z = __float2half(di * o2); g.w = __float2half(0.f);
    g2h[i] = g;
}

// ---- gather2: 16 lanes/node edge-split, bias + log_softmax -> out ----
__global__ void k_gather2(const Half4* __restrict__ g2h, const int* __restrict__ csr,
                          const int* __restrict__ row_start, const int* __restrict__ deg,
                          const float* __restrict__ dinv, const float* __restrict__ b2,
                          float* __restrict__ out, int n) {
    int idx = blockIdx.x * 256 + threadIdx.x;
    int i = idx >> 4, l = idx & 15;
    if (i >= n) return;
    int off = row_start[i], dg = deg[i];
    float v0 = 0.f, v1 = 0.f, v2 = 0.f;
    if (l == 0) {
        Half4 s = g2h[i];
        v0 = __half2float(s.x); v1 = __half2float(s.y); v2 = __half2float(s.z);
    }
    for (int e = l; e < dg; e += 16) {
        int s = csr[off + e];
        Half4 g = g2h[s];
        v0 += __half2float(g.x); v1 += __half2float(g.y); v2 += __half2float(g.z);
    }
    #pragma unroll
    for (int o = 1; o < 16; o <<= 1) {
        v0 += __shfl_xor(v0, o);
        v1 += __shfl_xor(v1, o);
        v2 += __shfl_xor(v2, o);
    }
    if (l >= 3) return;
    float di = dinv[i];
    float a0 = di * v0 + b2[0];
    float a1 = di * v1 + b2[1];
    float a2 = di * v2 + b2[2];
    float m = fmaxf(a0, fmaxf(a1, a2));
    float lse = logf(expf(a0 - m) + expf(a1 - m) + expf(a2 - m));
    float r = (l == 0) ? a0 : (l == 1) ? a1 : a2;
    out[(size_t)i * 3 + l] = r - m - lse;
}

// ======================== launch ========================
extern "C" void kernel_launch(void* const* d_in, const int* in_sizes, int n_in,
                              void* d_out, int out_size, void* d_ws, size_t ws_size,
                              hipStream_t stream) {
    const float* x  = (const float*)d_in[0];
    const int*   ei = (const int*)d_in[1];      // [2][E]
    const float* W1 = (const float*)d_in[2];    // [128][16]
    const float* b1 = (const float*)d_in[3];    // [16]
    const float* W2 = (const float*)d_in[4];    // [16][3]
    const float* b2 = (const float*)d_in[5];    // [3]
    float* out = (float*)d_out;

    const int n = in_sizes[0] / 128;   // 100000
    const int E = in_sizes[1] / 2;     // 1600000
    const int* src = ei;
    const int* dst = ei + E;

    const int NBK = (n + BNODES - 1) >> BSH;   // 196

    auto align = [](size_t v) { return (v + 255) & ~(size_t)255; };
    char* ws = (char*)d_ws;
    size_t o = 0;
    int* hist_t   = (int*)(ws + o); o = align(o + (size_t)NBK * P1 * 4);
    int* colpre_t = (int*)(ws + o); o = align(o + (size_t)NBK * P1 * 4);
    int* btot     = (int*)(ws + o); o = align(o + (size_t)NBK * 4);
    int* deg      = (int*)(ws + o); o = align(o + (size_t)n * 4);
    float* dinv   = (float*)(ws + o); o = align(o + (size_t)n * 4);
    int* row_start= (int*)(ws + o); o = align(o + (size_t)n * 4);
    unsigned int* staging = (unsigned int*)(ws + o); o = align(o + (size_t)NBK * BCAP * 4);
    int* csr      = (int*)(ws + o); o = align(o + (size_t)NBK * BCAP * 4);
    Half4* g1h    = (Half4*)(ws + o); o = align(o + (size_t)n * 4 * 8);
    Half4* g2h    = (Half4*)(ws + o); o = align(o + (size_t)n * 8);

    const int B = 256;
    int gGemm = (n + GROWS - 1) / GROWS;   // 1563
    int gn16  = (16 * n + B - 1) / B;      // 6250

    k1a_count<<<P1, B, 0, stream>>>(dst, hist_t, NBK, E);
    kscan1<<<NBK, B, 0, stream>>>(hist_t, colpre_t, btot, NBK);
    k1b_fat<<<P1 + gGemm, B, 0, stream>>>(src, dst, colpre_t, staging,
                                          x, W1, g1h, NBK, n, E);
    k2_bucket<<<NBK, 1024, 0, stream>>>(staging, btot, csr, deg, dinv, row_start, g1h, n);
    k_gather1<<<gn16, B, 0, stream>>>((const uint4*)g1h, csr, row_start, deg, dinv, b1, W2,
                                      g2h, n);
    k_gather2<<<gn16, B, 0, stream>>>(g2h, csr, row_start, deg, dinv, b2, out, n);
}